// Round 9
// baseline (250.265 us; speedup 1.0000x reference)
//
#include <hip/hip_runtime.h>
#include <stdint.h>

#define NN 16384
#define NE 128

typedef __attribute__((ext_vector_type(8))) short bf16x8;
typedef __attribute__((ext_vector_type(4))) float f32x4;
typedef uint32_t __attribute__((address_space(1))) gl_u32;
typedef uint32_t __attribute__((address_space(3))) lds_u32;

__device__ __forceinline__ uint32_t pack_bf16_2(float a, float b){
  union { float f; uint32_t u; } ua, ub;
  ua.f = a; ub.f = b;
  uint32_t x = ua.u, y = ub.u;
  x = (x + 0x7fffu + ((x >> 16) & 1u)) >> 16;   // RNE
  y = (y + 0x7fffu + ((y >> 16) & 1u)) >> 16;
  return (x & 0xffffu) | (y << 16);
}

// A [NN][NE] fp32 -> Ab [NN][NE] bf16
__global__ void conv_a_kernel(const float4* __restrict__ A, uint4* __restrict__ Ab){
  size_t t = (size_t)blockIdx.x * blockDim.x + threadIdx.x;
  float4 a = A[2*t], b = A[2*t+1];
  uint4 o;
  o.x = pack_bf16_2(a.x, a.y);
  o.y = pack_bf16_2(a.z, a.w);
  o.z = pack_bf16_2(b.x, b.y);
  o.w = pack_bf16_2(b.z, b.w);
  Ab[t] = o;
}

// B [NE][NN] fp32 + W[NE] -> Bt [NN][NE] bf16, Bt[n][k] = bf16(W[k]*B[k][n])
__global__ void conv_bt_kernel(const float* __restrict__ B, const float* __restrict__ W,
                               uint4* __restrict__ Bt){
  int n = blockIdx.x * 256 + threadIdx.x;
  #pragma unroll
  for (int kc = 0; kc < 16; ++kc){
    float f[8];
    #pragma unroll
    for (int j = 0; j < 8; ++j){
      int k = kc*8 + j;
      f[j] = W[k] * B[(size_t)k * NN + n];    // coalesced along n
    }
    uint4 o;
    o.x = pack_bf16_2(f[0], f[1]);
    o.y = pack_bf16_2(f[2], f[3]);
    o.z = pack_bf16_2(f[4], f[5]);
    o.w = pack_bf16_2(f[6], f[7]);
    Bt[(size_t)n * 16 + kc] = o;
  }
}

// R9: 64x128 tile (was 128x64). Same 48KB LDS -> 3 blocks/CU (R7's confirmed
// occupancy sweet spot; R8 showed 5 blocks regresses). Single variable: write
// piece width per C row doubles to 512B (halves DRAM page activations/byte —
// R8 post-mortem: 256B pieces at 64KB stride = ~4.2M activations for 1.07GB,
// 8x the fill kernel's per-byte rate; store-instruction pattern, L2 assembly,
// operand traffic, staging path all previously eliminated).
// Unchanged: XOR-swizzled LDS + gload_lds (linear dest, inverse-swz source,
// swz read), GM=16 m-fastest grouping, direct dword C-stores.
__launch_bounds__(256, 3)
__global__ void gemm_kernel(const uint4* __restrict__ Ab, const uint4* __restrict__ Bt,
                            float* __restrict__ C){
  __shared__ uint4 lds[3072];            // 48 KB: [0..1023] A 64rows, [1024..3071] B 128rows
  const int tid  = threadIdx.x;
  const int lane = tid & 63;
  const int bid  = blockIdx.x;
  const int grp  = bid >> 11;            // 16 groups of (16 m-tiles x 128 n-panels)
  const int r    = bid & 2047;
  const int m0   = (((grp << 4) + (r & 15)) << 6);   // m iterates fastest within group
  const int n0   = ((r >> 4) << 7);                  // 128 n-panels of 128

  // stage A-tile (4 chunks/thread) + B-tile (8 chunks/thread), swizzled source
  #pragma unroll
  for (int i = 0; i < 4; ++i){
    int cid = (i << 8) + tid;            // 0..1023 : row = cid>>4 (0..63), g = cid&15
    int row = cid >> 4;
    int gs  = (cid & 15) ^ (row & 7);
    __builtin_amdgcn_global_load_lds((const gl_u32*)(Ab + (((size_t)(m0 + row)) << 4) + gs),
                                     (lds_u32*)&lds[cid], 16, 0, 0);
  }
  #pragma unroll
  for (int i = 0; i < 8; ++i){
    int cid = (i << 8) + tid;            // 0..2047 : row = cid>>4 (0..127), g = cid&15
    int row = cid >> 4;
    int gs  = (cid & 15) ^ (row & 7);
    __builtin_amdgcn_global_load_lds((const gl_u32*)(Bt + (((size_t)(n0 + row)) << 4) + gs),
                                     (lds_u32*)&lds[1024 + cid], 16, 0, 0);
  }
  __syncthreads();                       // drains vmcnt -> LDS data visible

  const int w   = tid >> 6;
  const int wm  = (w >> 1) << 5;         // wave's 32-row block (2x2 wave grid)
  const int wn  = (w & 1) << 6;          // wave's 64-col block
  const int l15 = lane & 15;
  const int l4  = lane >> 4;

  f32x4 acc[2][4];
  #pragma unroll
  for (int i = 0; i < 2; ++i)
    #pragma unroll
    for (int j = 0; j < 4; ++j)
      acc[i][j] = (f32x4){0.f, 0.f, 0.f, 0.f};

  #pragma unroll
  for (int ks = 0; ks < 4; ++ks){        // K = 4 x 32
    bf16x8 af[2], bfr[4];
    const int c = (ks << 2) + l4;        // logical 16B chunk = 8 k-values
    #pragma unroll
    for (int mt = 0; mt < 2; ++mt){
      int row = wm + (mt << 4) + l15;    // A row (lane&15 = M index)
      af[mt] = *reinterpret_cast<const bf16x8*>(&lds[(row << 4) + (c ^ (row & 7))]);
    }
    #pragma unroll
    for (int nt = 0; nt < 4; ++nt){
      int row = wn + (nt << 4) + l15;    // Bt row (lane&15 = N index)
      bfr[nt] = *reinterpret_cast<const bf16x8*>(&lds[1024 + (row << 4) + (c ^ (row & 7))]);
    }
    #pragma unroll
    for (int mt = 0; mt < 2; ++mt)
      #pragma unroll
      for (int nt = 0; nt < 4; ++nt)
        acc[mt][nt] = __builtin_amdgcn_mfma_f32_16x16x32_bf16(af[mt], bfr[nt], acc[mt][nt], 0, 0, 0);
  }

  // C/D layout: col = lane&15 (n), row = (lane>>4)*4 + reg (m).
  // 4 consecutive nt-insts cover 256B; both wn halves combine to 512B/row.
  #pragma unroll
  for (int mt = 0; mt < 2; ++mt){
    #pragma unroll
    for (int j = 0; j < 4; ++j){
      size_t row = (size_t)(m0 + wm + (mt << 4) + (l4 << 2) + j);
      float* crow = C + row * NN + (size_t)(n0 + wn + l15);
      #pragma unroll
      for (int nt = 0; nt < 4; ++nt)
        crow[nt << 4] = acc[mt][nt][j];
    }
  }
}

// correctness fallback if workspace is too small (fp32 vector math, slow but exact-path)
__global__ void gemm_fallback(const float* __restrict__ A, const float* __restrict__ B,
                              const float* __restrict__ W, float* __restrict__ C){
  int n = blockIdx.x * 16 + threadIdx.x;
  int m = blockIdx.y * 16 + threadIdx.y;
  float acc = 0.f;
  for (int k = 0; k < NE; ++k)
    acc += A[(size_t)m * NE + k] * (W[k] * B[(size_t)k * NN + n]);
  C[(size_t)m * NN + n] = acc;
}

extern "C" void kernel_launch(void* const* d_in, const int* in_sizes, int n_in,
                              void* d_out, int out_size, void* d_ws, size_t ws_size,
                              hipStream_t stream){
  const float* A = (const float*)d_in[0];   // DV2_H [NN][NE]
  const float* B = (const float*)d_in[1];   // invDE_HT_DV2 [NE][NN]
  const float* W = (const float*)d_in[2];   // [NE]
  float* C = (float*)d_out;                 // [NN][NN] fp32

  const size_t need = (size_t)NN * NE * 2 * 2;   // Ab + Bt, 8 MB
  if (ws_size >= need){
    uint4* Ab = (uint4*)d_ws;
    uint4* Bt = (uint4*)((char*)d_ws + (size_t)NN * NE * 2);
    conv_a_kernel<<<NN * NE / (256 * 8), 256, 0, stream>>>((const float4*)A, Ab);
    conv_bt_kernel<<<NN / 256, 256, 0, stream>>>(B, W, Bt);
    gemm_kernel<<<(NN / 64) * (NN / 128), 256, 0, stream>>>(Ab, Bt, C);
  } else {
    dim3 g(NN / 16, NN / 16), b(16, 16);
    gemm_fallback<<<g, b, 0, stream>>>(A, B, W, C);
  }
}

// Round 10
// 235.098 us; speedup vs baseline: 1.0645x; 1.0645x over previous
//
#include <hip/hip_runtime.h>
#include <stdint.h>

#define NN 16384
#define NE 128

typedef __attribute__((ext_vector_type(8))) short bf16x8;
typedef __attribute__((ext_vector_type(4))) float f32x4;
typedef uint32_t __attribute__((address_space(1))) gl_u32;
typedef uint32_t __attribute__((address_space(3))) lds_u32;

__device__ __forceinline__ uint32_t pack_bf16_2(float a, float b){
  union { float f; uint32_t u; } ua, ub;
  ua.f = a; ub.f = b;
  uint32_t x = ua.u, y = ub.u;
  x = (x + 0x7fffu + ((x >> 16) & 1u)) >> 16;   // RNE
  y = (y + 0x7fffu + ((y >> 16) & 1u)) >> 16;
  return (x & 0xffffu) | (y << 16);
}

// A [NN][NE] fp32 -> Ab [NN][NE] bf16
__global__ void conv_a_kernel(const float4* __restrict__ A, uint4* __restrict__ Ab){
  size_t t = (size_t)blockIdx.x * blockDim.x + threadIdx.x;
  float4 a = A[2*t], b = A[2*t+1];
  uint4 o;
  o.x = pack_bf16_2(a.x, a.y);
  o.y = pack_bf16_2(a.z, a.w);
  o.z = pack_bf16_2(b.x, b.y);
  o.w = pack_bf16_2(b.z, b.w);
  Ab[t] = o;
}

// B [NE][NN] fp32 + W[NE] -> Bt [NN][NE] bf16, Bt[n][k] = bf16(W[k]*B[k][n])
__global__ void conv_bt_kernel(const float* __restrict__ B, const float* __restrict__ W,
                               uint4* __restrict__ Bt){
  int n = blockIdx.x * 256 + threadIdx.x;
  #pragma unroll
  for (int kc = 0; kc < 16; ++kc){
    float f[8];
    #pragma unroll
    for (int j = 0; j < 8; ++j){
      int k = kc*8 + j;
      f[j] = W[k] * B[(size_t)k * NN + n];    // coalesced along n
    }
    uint4 o;
    o.x = pack_bf16_2(f[0], f[1]);
    o.y = pack_bf16_2(f[2], f[3]);
    o.z = pack_bf16_2(f[4], f[5]);
    o.w = pack_bf16_2(f[6], f[7]);
    Bt[(size_t)n * 16 + kc] = o;
  }
}

// R10: intra-block panel pipeline (T3-lite). Block = 128 m-rows x 256 n-cols,
// processed as 8 panels of 32 cols. A (32KB) staged once and HOISTED TO
// REGISTERS (afr[4][4], no steady-state A ds_reads); B double-buffered
// (2 x 8KB). LDS = 48KB -> 3 blocks/CU (R7's confirmed occupancy optimum;
// R8/R9 showed more blocks or bigger B-tiles regress). Per panel: issue
// next-B stage -> store prev panel -> compute -> barrier (vmcnt drain is
// covered by the compute phase). Staged-bytes/output-byte 1.5 -> 0.75;
// 8 fine-grained store bursts per block keep the HBM write pipe fed.
__launch_bounds__(256, 3)
__global__ void gemm_kernel(const uint4* __restrict__ Ab, const uint4* __restrict__ Bt,
                            float* __restrict__ C){
  __shared__ uint4 ldsA[2048];           // 32 KB: A-tile 128 rows x 16 chunks
  __shared__ uint4 ldsB[2][512];         // 2 x 8 KB: B panels, 32 rows x 16 chunks
  const int tid  = threadIdx.x;
  const int lane = tid & 63;
  const int bid  = blockIdx.x;
  const int grp  = bid >> 10;            // 8 groups of 1024
  const int r    = bid & 1023;
  const int m0   = (((grp << 4) + (r & 15)) << 7);   // m-fastest x16 (R3's win)
  const int n0r  = ((r >> 4) << 8);                  // 64 n-ranges of 256

  // prologue: stage A (8 chunks/thread) + B panel 0 (2 chunks/thread)
  #pragma unroll
  for (int i = 0; i < 8; ++i){
    int cid = (i << 8) + tid;            // row = cid>>4 (0..127), g = cid&15
    int row = cid >> 4;
    int gs  = (cid & 15) ^ (row & 7);
    __builtin_amdgcn_global_load_lds((const gl_u32*)(Ab + (((size_t)(m0 + row)) << 4) + gs),
                                     (lds_u32*)&ldsA[cid], 16, 0, 0);
  }
  #pragma unroll
  for (int i = 0; i < 2; ++i){
    int cid = (i << 8) + tid;            // row = cid>>4 (0..31)
    int row = cid >> 4;
    int gs  = (cid & 15) ^ (row & 7);
    __builtin_amdgcn_global_load_lds((const gl_u32*)(Bt + (((size_t)(n0r + row)) << 4) + gs),
                                     (lds_u32*)&ldsB[0][cid], 16, 0, 0);
  }
  __syncthreads();                       // compiler drains vmcnt before s_barrier

  const int w   = tid >> 6;
  const int wm  = (w >> 1) << 6;         // wave's 64-row block of the 128
  const int wn  = (w & 1) << 4;          // wave's 16-col block of the 32-col panel
  const int l15 = lane & 15;
  const int l4  = lane >> 4;

  // hoist A fragments to registers once: afr[mt][ks] (64 VGPR)
  bf16x8 afr[4][4];
  #pragma unroll
  for (int mt = 0; mt < 4; ++mt){
    int row = wm + (mt << 4) + l15;
    #pragma unroll
    for (int ks = 0; ks < 4; ++ks){
      int c = (ks << 2) + l4;
      afr[mt][ks] = *reinterpret_cast<const bf16x8*>(&ldsA[(row << 4) + (c ^ (row & 7))]);
    }
  }

  f32x4 acc[2][4];                       // [pipeline slot][mt] — static-indexed via unroll

  #pragma unroll
  for (int p = 0; p < 8; ++p){
    const int cur = p & 1;
    // (1) issue next B-panel stage (2 gload_lds/thread) — oldest vmem this iter
    if (p < 7){
      #pragma unroll
      for (int i = 0; i < 2; ++i){
        int cid = (i << 8) + tid;
        int row = cid >> 4;
        int gs  = (cid & 15) ^ (row & 7);
        __builtin_amdgcn_global_load_lds(
            (const gl_u32*)(Bt + (((size_t)(n0r + ((p + 1) << 5) + row)) << 4) + gs),
            (lds_u32*)&ldsB[1 - cur][cid], 16, 0, 0);
      }
    }
    // (2) store previous panel (16 dwords/thread) — retires under compute
    if (p > 0){
      #pragma unroll
      for (int mt = 0; mt < 4; ++mt){
        #pragma unroll
        for (int j = 0; j < 4; ++j){
          size_t row = (size_t)(m0 + wm + (mt << 4) + (l4 << 2) + j);
          C[row * NN + (size_t)(n0r + ((p - 1) << 5) + wn + l15)] = acc[1 - cur][mt][j];
        }
      }
    }
    // (3) compute panel p: 4 ds_read_b128 + 16 MFMA
    #pragma unroll
    for (int mt = 0; mt < 4; ++mt) acc[cur][mt] = (f32x4){0.f, 0.f, 0.f, 0.f};
    #pragma unroll
    for (int ks = 0; ks < 4; ++ks){
      int c    = (ks << 2) + l4;
      int brow = wn + l15;               // 0..31
      bf16x8 bfr = *reinterpret_cast<const bf16x8*>(&ldsB[cur][(brow << 4) + (c ^ (brow & 7))]);
      #pragma unroll
      for (int mt = 0; mt < 4; ++mt)
        acc[cur][mt] = __builtin_amdgcn_mfma_f32_16x16x32_bf16(afr[mt][ks], bfr, acc[cur][mt], 0, 0, 0);
    }
    // (4) barrier: next buf ready, prev reads done (drains covered by compute)
    __syncthreads();
  }
  // final store: panel 7 (acc slot 1)
  #pragma unroll
  for (int mt = 0; mt < 4; ++mt){
    #pragma unroll
    for (int j = 0; j < 4; ++j){
      size_t row = (size_t)(m0 + wm + (mt << 4) + (l4 << 2) + j);
      C[row * NN + (size_t)(n0r + (7 << 5) + wn + l15)] = acc[1][mt][j];
    }
  }
}

// correctness fallback if workspace is too small (fp32 vector math, slow but exact-path)
__global__ void gemm_fallback(const float* __restrict__ A, const float* __restrict__ B,
                              const float* __restrict__ W, float* __restrict__ C){
  int n = blockIdx.x * 16 + threadIdx.x;
  int m = blockIdx.y * 16 + threadIdx.y;
  float acc = 0.f;
  for (int k = 0; k < NE; ++k)
    acc += A[(size_t)m * NE + k] * (W[k] * B[(size_t)k * NN + n]);
  C[(size_t)m * NN + n] = acc;
}

extern "C" void kernel_launch(void* const* d_in, const int* in_sizes, int n_in,
                              void* d_out, int out_size, void* d_ws, size_t ws_size,
                              hipStream_t stream){
  const float* A = (const float*)d_in[0];   // DV2_H [NN][NE]
  const float* B = (const float*)d_in[1];   // invDE_HT_DV2 [NE][NN]
  const float* W = (const float*)d_in[2];   // [NE]
  float* C = (float*)d_out;                 // [NN][NN] fp32

  const size_t need = (size_t)NN * NE * 2 * 2;   // Ab + Bt, 8 MB
  if (ws_size >= need){
    uint4* Ab = (uint4*)d_ws;
    uint4* Bt = (uint4*)((char*)d_ws + (size_t)NN * NE * 2);
    conv_a_kernel<<<NN * NE / (256 * 8), 256, 0, stream>>>((const float4*)A, Ab);
    conv_bt_kernel<<<NN / 256, 256, 0, stream>>>(B, W, Bt);
    gemm_kernel<<<(NN / 128) * (NN / 256), 256, 0, stream>>>(Ab, Bt, C);
  } else {
    dim3 g(NN / 16, NN / 16), b(16, 16);
    gemm_fallback<<<g, b, 0, stream>>>(A, B, W, C);
  }
}

// Round 11
// 218.133 us; speedup vs baseline: 1.1473x; 1.0778x over previous
//
#include <hip/hip_runtime.h>
#include <stdint.h>

#define NN 16384
#define NE 128

typedef __attribute__((ext_vector_type(8))) short bf16x8;
typedef __attribute__((ext_vector_type(4))) float f32x4;
typedef uint32_t __attribute__((address_space(1))) gl_u32;
typedef uint32_t __attribute__((address_space(3))) lds_u32;

__device__ __forceinline__ uint32_t pack_bf16_2(float a, float b){
  union { float f; uint32_t u; } ua, ub;
  ua.f = a; ub.f = b;
  uint32_t x = ua.u, y = ub.u;
  x = (x + 0x7fffu + ((x >> 16) & 1u)) >> 16;   // RNE
  y = (y + 0x7fffu + ((y >> 16) & 1u)) >> 16;
  return (x & 0xffffu) | (y << 16);
}

// A [NN][NE] fp32 -> Ab [NN][NE] bf16
__global__ void conv_a_kernel(const float4* __restrict__ A, uint4* __restrict__ Ab){
  size_t t = (size_t)blockIdx.x * blockDim.x + threadIdx.x;
  float4 a = A[2*t], b = A[2*t+1];
  uint4 o;
  o.x = pack_bf16_2(a.x, a.y);
  o.y = pack_bf16_2(a.z, a.w);
  o.z = pack_bf16_2(b.x, b.y);
  o.w = pack_bf16_2(b.z, b.w);
  Ab[t] = o;
}

// B [NE][NN] fp32 + W[NE] -> Bt [NN][NE] bf16, Bt[n][k] = bf16(W[k]*B[k][n])
__global__ void conv_bt_kernel(const float* __restrict__ B, const float* __restrict__ W,
                               uint4* __restrict__ Bt){
  int n = blockIdx.x * 256 + threadIdx.x;
  #pragma unroll
  for (int kc = 0; kc < 16; ++kc){
    float f[8];
    #pragma unroll
    for (int j = 0; j < 8; ++j){
      int k = kc*8 + j;
      f[j] = W[k] * B[(size_t)k * NN + n];    // coalesced along n
    }
    uint4 o;
    o.x = pack_bf16_2(f[0], f[1]);
    o.y = pack_bf16_2(f[2], f[3]);
    o.z = pack_bf16_2(f[4], f[5]);
    o.w = pack_bf16_2(f[6], f[7]);
    Bt[(size_t)n * 16 + kc] = o;
  }
}

// FINAL (R7 structure, best of 10 experiments: 217.6us ~ 5.1 TB/s effective,
// 78% of the co-measured pure-write fill ceiling).
// 128x64 tile -> 48KB LDS -> 3 blocks/CU (occupancy bracketed: 2=227, 3=218,
// 5=249). XOR-swizzled LDS fed by global_load_lds width=16 (linear dest,
// inverse-swizzled source, swizzled ds_read_b128 -> 0 bank conflicts).
// GM=16 m-fastest grid grouping keeps the group's Ab slice + shared Bt panel
// L2-hot (+10us vs naive). Direct dword C-stores: 4 consecutive insts cover a
// contiguous 256B row span; L2 write-back assembles full lines (beats
// LDS-transpose epilogue, NT stores, and swapped-operand variants).
__launch_bounds__(256, 3)
__global__ void gemm_kernel(const uint4* __restrict__ Ab, const uint4* __restrict__ Bt,
                            float* __restrict__ C){
  __shared__ uint4 lds[3072];            // 48 KB: [0..2047] A 128rows, [2048..3071] B 64rows
  const int tid  = threadIdx.x;
  const int lane = tid & 63;
  const int bid  = blockIdx.x;
  const int grp  = bid >> 12;            // bid / (16*256): 8 groups
  const int r    = bid & 4095;
  const int m0   = (((grp << 4) + (r & 15)) << 7);   // m iterates fastest within group
  const int n0   = ((r >> 4) << 6);                  // 256 n-panels of 64

  // stage A-tile (8 chunks/thread) + B-tile (4 chunks/thread), swizzled source
  #pragma unroll
  for (int i = 0; i < 8; ++i){
    int cid = (i << 8) + tid;            // 0..2047 : row = cid>>4, g = cid&15
    int row = cid >> 4;
    int gs  = (cid & 15) ^ (row & 7);
    __builtin_amdgcn_global_load_lds((const gl_u32*)(Ab + (((size_t)(m0 + row)) << 4) + gs),
                                     (lds_u32*)&lds[cid], 16, 0, 0);
  }
  #pragma unroll
  for (int i = 0; i < 4; ++i){
    int cid = (i << 8) + tid;            // 0..1023 : row = cid>>4, g = cid&15
    int row = cid >> 4;
    int gs  = (cid & 15) ^ (row & 7);
    __builtin_amdgcn_global_load_lds((const gl_u32*)(Bt + (((size_t)(n0 + row)) << 4) + gs),
                                     (lds_u32*)&lds[2048 + cid], 16, 0, 0);
  }
  __syncthreads();                       // drains vmcnt -> LDS data visible

  const int w   = tid >> 6;
  const int wm  = (w >> 1) << 6;         // wave's 64-row block (2x2 wave grid)
  const int wn  = (w & 1) << 5;          // wave's 32-col block
  const int l15 = lane & 15;
  const int l4  = lane >> 4;

  f32x4 acc[4][2];
  #pragma unroll
  for (int i = 0; i < 4; ++i)
    #pragma unroll
    for (int j = 0; j < 2; ++j)
      acc[i][j] = (f32x4){0.f, 0.f, 0.f, 0.f};

  #pragma unroll
  for (int ks = 0; ks < 4; ++ks){        // K = 4 x 32
    bf16x8 af[4], bfr[2];
    const int c = (ks << 2) + l4;        // logical 16B chunk = 8 k-values
    #pragma unroll
    for (int mt = 0; mt < 4; ++mt){
      int row = wm + (mt << 4) + l15;    // A row (lane&15 = M index)
      af[mt] = *reinterpret_cast<const bf16x8*>(&lds[(row << 4) + (c ^ (row & 7))]);
    }
    #pragma unroll
    for (int nt = 0; nt < 2; ++nt){
      int row = wn + (nt << 4) + l15;    // Bt row (lane&15 = N index)
      bfr[nt] = *reinterpret_cast<const bf16x8*>(&lds[2048 + (row << 4) + (c ^ (row & 7))]);
    }
    #pragma unroll
    for (int mt = 0; mt < 4; ++mt)
      #pragma unroll
      for (int nt = 0; nt < 2; ++nt)
        acc[mt][nt] = __builtin_amdgcn_mfma_f32_16x16x32_bf16(af[mt], bfr[nt], acc[mt][nt], 0, 0, 0);
  }

  // C/D layout: col = lane&15 (n), row = (lane>>4)*4 + reg (m).
  #pragma unroll
  for (int mt = 0; mt < 4; ++mt){
    #pragma unroll
    for (int j = 0; j < 4; ++j){
      size_t row = (size_t)(m0 + wm + (mt << 4) + (l4 << 2) + j);
      float* crow = C + row * NN + (size_t)(n0 + wn + l15);
      #pragma unroll
      for (int nt = 0; nt < 2; ++nt)
        crow[nt << 4] = acc[mt][nt][j];
    }
  }
}

// correctness fallback if workspace is too small (fp32 vector math, slow but exact-path)
__global__ void gemm_fallback(const float* __restrict__ A, const float* __restrict__ B,
                              const float* __restrict__ W, float* __restrict__ C){
  int n = blockIdx.x * 16 + threadIdx.x;
  int m = blockIdx.y * 16 + threadIdx.y;
  float acc = 0.f;
  for (int k = 0; k < NE; ++k)
    acc += A[(size_t)m * NE + k] * (W[k] * B[(size_t)k * NN + n]);
  C[(size_t)m * NN + n] = acc;
}

extern "C" void kernel_launch(void* const* d_in, const int* in_sizes, int n_in,
                              void* d_out, int out_size, void* d_ws, size_t ws_size,
                              hipStream_t stream){
  const float* A = (const float*)d_in[0];   // DV2_H [NN][NE]
  const float* B = (const float*)d_in[1];   // invDE_HT_DV2 [NE][NN]
  const float* W = (const float*)d_in[2];   // [NE]
  float* C = (float*)d_out;                 // [NN][NN] fp32

  const size_t need = (size_t)NN * NE * 2 * 2;   // Ab + Bt, 8 MB
  if (ws_size >= need){
    uint4* Ab = (uint4*)d_ws;
    uint4* Bt = (uint4*)((char*)d_ws + (size_t)NN * NE * 2);
    conv_a_kernel<<<NN * NE / (256 * 8), 256, 0, stream>>>((const float4*)A, Ab);
    conv_bt_kernel<<<NN / 256, 256, 0, stream>>>(B, W, Bt);
    gemm_kernel<<<(NN / 128) * (NN / 64), 256, 0, stream>>>(Ab, Bt, C);
  } else {
    dim3 g(NN / 16, NN / 16), b(16, 16);
    gemm_fallback<<<g, b, 0, stream>>>(A, B, W, C);
  }
}